// Round 1
// baseline (706.063 us; speedup 1.0000x reference)
//
#include <hip/hip_runtime.h>

#define N_NODES 50000
#define N_EDGES 1600000
#define HD 128   // H*D = 8*16

// ---------------- CSR construction ----------------

__global__ void hist_kernel(const int* __restrict__ dst, int* __restrict__ counts) {
    int i = blockIdx.x * blockDim.x + threadIdx.x;
    int stride = gridDim.x * blockDim.x;
    for (int e = i; e < N_EDGES; e += stride)
        atomicAdd(&counts[dst[e]], 1);
}

__global__ void scan_kernel(const int* __restrict__ counts, int* __restrict__ row_ptr,
                            int* __restrict__ cursor) {
    const int T = 1024;
    int t = threadIdx.x;
    int chunk = (N_NODES + T - 1) / T;   // 49
    int beg = t * chunk;
    int end = min(beg + chunk, N_NODES);
    if (beg > N_NODES) beg = N_NODES;
    int sum = 0;
    for (int i = beg; i < end; ++i) sum += counts[i];
    __shared__ int part[T];
    part[t] = sum;
    __syncthreads();
    // Hillis-Steele inclusive scan over 1024 partials
    for (int off = 1; off < T; off <<= 1) {
        int v = (t >= off) ? part[t - off] : 0;
        __syncthreads();
        part[t] += v;
        __syncthreads();
    }
    int run = part[t] - sum;   // exclusive prefix of this thread's chunk
    for (int i = beg; i < end; ++i) {
        row_ptr[i] = run;
        cursor[i]  = run;
        run += counts[i];
    }
    if (t == T - 1) row_ptr[N_NODES] = run;   // == E
}

__global__ void scatter_kernel(const int* __restrict__ src, const int* __restrict__ dst,
                               int* __restrict__ cursor, int* __restrict__ col_src) {
    int i = blockIdx.x * blockDim.x + threadIdx.x;
    int stride = gridDim.x * blockDim.x;
    for (int e = i; e < N_EDGES; e += stride) {
        int d = dst[e];
        int pos = atomicAdd(&cursor[d], 1);
        col_src[pos] = src[e];
    }
}

// ---------------- Q/K/V projection (3 fused fp32 GEMMs) ----------------
// Block: 256 threads, 32 rows x 128 cols tile. h tile staged in LDS.
// Thread (c = t&127, r0 = (t>>7)*16) computes 16 rows for its column, all 3 mats.

__global__ __launch_bounds__(256) void proj_kernel(
    const float* __restrict__ h,
    const float* __restrict__ WQ, const float* __restrict__ WK, const float* __restrict__ WV,
    const float* __restrict__ bQ, const float* __restrict__ bK, const float* __restrict__ bV,
    float* __restrict__ Q, float* __restrict__ K, float* __restrict__ V) {
    __shared__ float hs[32][128];
    int t = threadIdx.x;
    int row0 = blockIdx.x * 32;
    for (int i = t; i < 32 * 128; i += 256) {
        int r = i >> 7, c = i & 127;
        int gr = row0 + r;
        hs[r][c] = (gr < N_NODES) ? h[gr * 128 + c] : 0.0f;
    }
    __syncthreads();
    int c = t & 127;
    int r0 = (t >> 7) * 16;   // 0 or 16, wave-uniform
    float accQ[16], accK[16], accV[16];
#pragma unroll
    for (int r = 0; r < 16; ++r) { accQ[r] = 0.f; accK[r] = 0.f; accV[r] = 0.f; }
#pragma unroll 4
    for (int k = 0; k < 128; ++k) {
        float wq = WQ[k * 128 + c];
        float wk = WK[k * 128 + c];
        float wv = WV[k * 128 + c];
#pragma unroll
        for (int r = 0; r < 16; ++r) {
            float hv = hs[r0 + r][k];    // wave-uniform address -> LDS broadcast
            accQ[r] = fmaf(hv, wq, accQ[r]);
            accK[r] = fmaf(hv, wk, accK[r]);
            accV[r] = fmaf(hv, wv, accV[r]);
        }
    }
    float bq = bQ[c], bk = bK[c], bv = bV[c];
#pragma unroll
    for (int r = 0; r < 16; ++r) {
        int gr = row0 + r0 + r;
        if (gr < N_NODES) {
            Q[gr * 128 + c] = accQ[r] + bq;
            K[gr * 128 + c] = accK[r] + bk;
            V[gr * 128 + c] = accV[r] + bv;
        }
    }
}

// ---------------- Gather attention ----------------
// One wave (64 lanes) per dst node. Lane t holds dims {2t, 2t+1} (float2).
// Head = t>>3 (8 lanes per head, 16 dims). Dot reduced via shfl_xor width 8.

__global__ __launch_bounds__(64) void attn_kernel(
    const float* __restrict__ Q, const float* __restrict__ K, const float* __restrict__ V,
    const int* __restrict__ row_ptr, const int* __restrict__ col_src,
    float* __restrict__ out) {
    int n = blockIdx.x;
    int t = threadIdx.x;   // 0..63
    const float2* Q2 = (const float2*)Q;
    const float2* K2 = (const float2*)K;
    const float2* V2 = (const float2*)V;
    float2 q = Q2[(size_t)n * 64 + t];
    int beg = row_ptr[n], end = row_ptr[n + 1];
    float ax = 0.f, ay = 0.f, z = 0.f;
    __shared__ int s_src[64];
    for (int base = beg; base < end; base += 64) {
        int m = min(64, end - base);
        if (t < m) s_src[t] = col_src[base + t];
        __syncthreads();
        for (int j = 0; j < m; ++j) {
            int s = s_src[j];
            float2 kk = K2[(size_t)s * 64 + t];
            float p = kk.x * q.x + kk.y * q.y;
            p += __shfl_xor(p, 4, 8);
            p += __shfl_xor(p, 2, 8);
            p += __shfl_xor(p, 1, 8);
            float sc = __expf(fminf(fmaxf(p * 0.25f, -5.f), 5.f));
            float2 vv = V2[(size_t)s * 64 + t];
            ax = fmaf(sc, vv.x, ax);
            ay = fmaf(sc, vv.y, ay);
            z += sc;
        }
        __syncthreads();
    }
    float2 o;
    o.x = ax / z;
    o.y = ay / z;
    ((float2*)out)[(size_t)n * 64 + t] = o;
}

// ---------------- launch ----------------

extern "C" void kernel_launch(void* const* d_in, const int* in_sizes, int n_in,
                              void* d_out, int out_size, void* d_ws, size_t ws_size,
                              hipStream_t stream) {
    const float* h  = (const float*)d_in[0];
    const int*   src = (const int*)d_in[1];
    const int*   dst = (const int*)d_in[2];
    const float* WQ = (const float*)d_in[3];
    const float* WK = (const float*)d_in[4];
    const float* WV = (const float*)d_in[5];
    const float* bQ = (const float*)d_in[6];
    const float* bK = (const float*)d_in[7];
    const float* bV = (const float*)d_in[8];
    float* out = (float*)d_out;

    // workspace layout (~84 MB)
    float* Q = (float*)d_ws;
    float* K = Q + (size_t)N_NODES * HD;
    float* V = K + (size_t)N_NODES * HD;
    int* row_ptr = (int*)(V + (size_t)N_NODES * HD);
    int* cursor  = row_ptr + (N_NODES + 1);
    int* counts  = cursor + N_NODES;
    int* col_src = counts + N_NODES;

    hipMemsetAsync(counts, 0, N_NODES * sizeof(int), stream);
    hist_kernel<<<2048, 256, 0, stream>>>(dst, counts);
    scan_kernel<<<1, 1024, 0, stream>>>(counts, row_ptr, cursor);
    scatter_kernel<<<2048, 256, 0, stream>>>(src, dst, cursor, col_src);
    proj_kernel<<<(N_NODES + 31) / 32, 256, 0, stream>>>(h, WQ, WK, WV, bQ, bK, bV, Q, K, V);
    attn_kernel<<<N_NODES, 64, 0, stream>>>(Q, K, V, row_ptr, col_src, out);
}

// Round 2
// 602.169 us; speedup vs baseline: 1.1725x; 1.1725x over previous
//
#include <hip/hip_runtime.h>
#include <hip/hip_bf16.h>

#define N_NODES 50000
#define N_EDGES 1600000
#define HD 128   // H*D = 8*16

// ---------------- CSR construction ----------------

__global__ void hist_kernel(const int* __restrict__ dst, int* __restrict__ counts) {
    int i = blockIdx.x * blockDim.x + threadIdx.x;
    int stride = gridDim.x * blockDim.x;
    for (int e = i; e < N_EDGES; e += stride)
        atomicAdd(&counts[dst[e]], 1);
}

__global__ void scan_kernel(const int* __restrict__ counts, int* __restrict__ row_ptr,
                            int* __restrict__ cursor) {
    const int T = 1024;
    int t = threadIdx.x;
    int chunk = (N_NODES + T - 1) / T;   // 49
    int beg = t * chunk;
    int end = min(beg + chunk, N_NODES);
    if (beg > N_NODES) beg = N_NODES;
    int sum = 0;
    for (int i = beg; i < end; ++i) sum += counts[i];
    __shared__ int part[T];
    part[t] = sum;
    __syncthreads();
    for (int off = 1; off < T; off <<= 1) {
        int v = (t >= off) ? part[t - off] : 0;
        __syncthreads();
        part[t] += v;
        __syncthreads();
    }
    int run = part[t] - sum;
    for (int i = beg; i < end; ++i) {
        row_ptr[i] = run;
        cursor[i]  = run;
        run += counts[i];
    }
    if (t == T - 1) row_ptr[N_NODES] = run;
}

__global__ void scatter_kernel(const int* __restrict__ src, const int* __restrict__ dst,
                               int* __restrict__ cursor, int* __restrict__ col_src) {
    int i = blockIdx.x * blockDim.x + threadIdx.x;
    int stride = gridDim.x * blockDim.x;
    for (int e = i; e < N_EDGES; e += stride) {
        int d = dst[e];
        int pos = atomicAdd(&cursor[d], 1);
        col_src[pos] = src[e];
    }
}

// ---------------- Q/K/V projection (Q fp32, K/V bf16 out) ----------------

__global__ __launch_bounds__(256) void proj_kernel(
    const float* __restrict__ h,
    const float* __restrict__ WQ, const float* __restrict__ WK, const float* __restrict__ WV,
    const float* __restrict__ bQ, const float* __restrict__ bK, const float* __restrict__ bV,
    float* __restrict__ Q, __hip_bfloat16* __restrict__ Kb, __hip_bfloat16* __restrict__ Vb) {
    __shared__ float hs[32][128];
    int t = threadIdx.x;
    int row0 = blockIdx.x * 32;
    for (int i = t; i < 32 * 128; i += 256) {
        int r = i >> 7, c = i & 127;
        int gr = row0 + r;
        hs[r][c] = (gr < N_NODES) ? h[gr * 128 + c] : 0.0f;
    }
    __syncthreads();
    int c = t & 127;
    int r0 = (t >> 7) * 16;
    float accQ[16], accK[16], accV[16];
#pragma unroll
    for (int r = 0; r < 16; ++r) { accQ[r] = 0.f; accK[r] = 0.f; accV[r] = 0.f; }
#pragma unroll 4
    for (int k = 0; k < 128; ++k) {
        float wq = WQ[k * 128 + c];
        float wk = WK[k * 128 + c];
        float wv = WV[k * 128 + c];
#pragma unroll
        for (int r = 0; r < 16; ++r) {
            float hv = hs[r0 + r][k];
            accQ[r] = fmaf(hv, wq, accQ[r]);
            accK[r] = fmaf(hv, wk, accK[r]);
            accV[r] = fmaf(hv, wv, accV[r]);
        }
    }
    float bq = bQ[c], bk = bK[c], bv = bV[c];
#pragma unroll
    for (int r = 0; r < 16; ++r) {
        int gr = row0 + r0 + r;
        if (gr < N_NODES) {
            Q[gr * 128 + c]  = accQ[r] + bq;
            Kb[gr * 128 + c] = __float2bfloat16(accK[r] + bk);
            Vb[gr * 128 + c] = __float2bfloat16(accV[r] + bv);
        }
    }
}

// ---------------- Gather attention ----------------
// One wave per dst node. Wave split into 4 quarters; each quarter handles one
// edge per inner iteration (4 edges in flight). Lane p (0..15) in a quarter
// covers dims 8p..8p+7 (uint4 = 8 bf16). Head = p>>1; dot reduced in-lane
// (8 dims) + shfl_xor(1). Quarters combined at the end via shfl_xor(16/32).

__device__ __forceinline__ float blo(unsigned u) { return __uint_as_float(u << 16); }
__device__ __forceinline__ float bhi(unsigned u) { return __uint_as_float(u & 0xffff0000u); }

__global__ __launch_bounds__(64) void attn_kernel(
    const float* __restrict__ Q,
    const __hip_bfloat16* __restrict__ Kb, const __hip_bfloat16* __restrict__ Vb,
    const int* __restrict__ row_ptr, const int* __restrict__ col_src,
    float* __restrict__ out) {
    int n = blockIdx.x;
    int t = threadIdx.x;
    int q4 = t >> 4;     // quarter 0..3
    int p  = t & 15;     // lane in quarter

    const float4* Qv = (const float4*)(Q + (size_t)n * 128 + p * 8);
    float4 qa = Qv[0], qb = Qv[1];

    int beg = row_ptr[n], end = row_ptr[n + 1];
    float acc[8];
#pragma unroll
    for (int d = 0; d < 8; ++d) acc[d] = 0.f;
    float z = 0.f;

    for (int base = beg; base < end; base += 64) {
        int mm = min(64, end - base);
        // each lane stages one edge index in a register
        int e_l = col_src[(base + t < end) ? (base + t) : beg];
        int iters = (mm + 3) >> 2;
        for (int i = 0; i < iters; ++i) {
            int ei = 4 * i + q4;
            bool valid = ei < mm;
            int s = __shfl(e_l, ei);   // bpermute broadcast
            const uint4* Kv = (const uint4*)((const unsigned short*)Kb + (size_t)s * 128 + p * 8);
            uint4 kr = *Kv;
            const uint4* Vv = (const uint4*)((const unsigned short*)Vb + (size_t)s * 128 + p * 8);
            uint4 vr = *Vv;
            float dot = blo(kr.x) * qa.x + bhi(kr.x) * qa.y
                      + blo(kr.y) * qa.z + bhi(kr.y) * qa.w
                      + blo(kr.z) * qb.x + bhi(kr.z) * qb.y
                      + blo(kr.w) * qb.z + bhi(kr.w) * qb.w;
            dot += __shfl_xor(dot, 1);
            float sc = __expf(fminf(fmaxf(dot * 0.25f, -5.f), 5.f));
            if (!valid) sc = 0.f;
            acc[0] = fmaf(sc, blo(vr.x), acc[0]);
            acc[1] = fmaf(sc, bhi(vr.x), acc[1]);
            acc[2] = fmaf(sc, blo(vr.y), acc[2]);
            acc[3] = fmaf(sc, bhi(vr.y), acc[3]);
            acc[4] = fmaf(sc, blo(vr.z), acc[4]);
            acc[5] = fmaf(sc, bhi(vr.z), acc[5]);
            acc[6] = fmaf(sc, blo(vr.w), acc[6]);
            acc[7] = fmaf(sc, bhi(vr.w), acc[7]);
            z += sc;
        }
    }
    // combine quarters
#pragma unroll
    for (int d = 0; d < 8; ++d) {
        acc[d] += __shfl_xor(acc[d], 16);
        acc[d] += __shfl_xor(acc[d], 32);
    }
    z += __shfl_xor(z, 16);
    z += __shfl_xor(z, 32);

    if (q4 == 0) {
        float inv = 1.f / z;
        float4 o0 = {acc[0] * inv, acc[1] * inv, acc[2] * inv, acc[3] * inv};
        float4 o1 = {acc[4] * inv, acc[5] * inv, acc[6] * inv, acc[7] * inv};
        float4* O = (float4*)(out + (size_t)n * 128 + p * 8);
        O[0] = o0;
        O[1] = o1;
    }
}

// ---------------- launch ----------------

extern "C" void kernel_launch(void* const* d_in, const int* in_sizes, int n_in,
                              void* d_out, int out_size, void* d_ws, size_t ws_size,
                              hipStream_t stream) {
    const float* h  = (const float*)d_in[0];
    const int*   src = (const int*)d_in[1];
    const int*   dst = (const int*)d_in[2];
    const float* WQ = (const float*)d_in[3];
    const float* WK = (const float*)d_in[4];
    const float* WV = (const float*)d_in[5];
    const float* bQ = (const float*)d_in[6];
    const float* bK = (const float*)d_in[7];
    const float* bV = (const float*)d_in[8];
    float* out = (float*)d_out;

    const size_t NH = (size_t)N_NODES * HD;   // 6,400,000
    float* Q = (float*)d_ws;
    __hip_bfloat16* Kb = (__hip_bfloat16*)(Q + NH);
    __hip_bfloat16* Vb = Kb + NH;
    int* row_ptr = (int*)(Vb + NH);
    int* cursor  = row_ptr + (N_NODES + 1);
    int* counts  = cursor + N_NODES;
    int* col_src = counts + N_NODES;

    hipMemsetAsync(counts, 0, N_NODES * sizeof(int), stream);
    hist_kernel<<<2048, 256, 0, stream>>>(dst, counts);
    scan_kernel<<<1, 1024, 0, stream>>>(counts, row_ptr, cursor);
    scatter_kernel<<<2048, 256, 0, stream>>>(src, dst, cursor, col_src);
    proj_kernel<<<(N_NODES + 31) / 32, 256, 0, stream>>>(h, WQ, WK, WV, bQ, bK, bV, Q, Kb, Vb);
    attn_kernel<<<N_NODES, 64, 0, stream>>>(Q, Kb, Vb, row_ptr, col_src, out);
}

// Round 3
// 334.068 us; speedup vs baseline: 2.1135x; 1.8025x over previous
//
#include <hip/hip_runtime.h>
#include <hip/hip_bf16.h>

#define N_NODES 50000
#define N_EDGES 1600000
#define HD 128                                   // H*D = 8*16
#define CHUNK 2048
#define NCHUNK ((N_EDGES + CHUNK - 1) / CHUNK)   // 782
#define NBUCKET ((N_NODES + 255) / 256)          // 196

// ================= CSR build: two-level counting sort, NO global atomics ====

// K1: per-chunk coarse histogram (bucket = dst>>8)
__global__ __launch_bounds__(256) void k_chunkhist(const int* __restrict__ dst,
                                                   int* __restrict__ chunkhist) {
    __shared__ int hist[NBUCKET];
    int t = threadIdx.x, c = blockIdx.x;
    for (int i = t; i < NBUCKET; i += 256) hist[i] = 0;
    __syncthreads();
    int e0 = c * CHUNK;
    int cnt = min(CHUNK, N_EDGES - e0);
    for (int i = t; i < cnt; i += 256)
        atomicAdd(&hist[dst[e0 + i] >> 8], 1);
    __syncthreads();
    for (int i = t; i < NBUCKET; i += 256)
        chunkhist[c * NBUCKET + i] = hist[i];
}

// K2a: total edges per bucket
__global__ __launch_bounds__(256) void k_btot(const int* __restrict__ chunkhist,
                                              int* __restrict__ btot) {
    int b = blockIdx.x, t = threadIdx.x;
    int s = 0;
    for (int c = t; c < NCHUNK; c += 256) s += chunkhist[c * NBUCKET + b];
    __shared__ int part[256];
    part[t] = s;
    __syncthreads();
    for (int off = 128; off > 0; off >>= 1) {
        if (t < off) part[t] += part[t + off];
        __syncthreads();
    }
    if (t == 0) btot[b] = part[0];
}

// K2b: exclusive scan of bucket totals -> bucket_ptr[NBUCKET+1]
__global__ __launch_bounds__(256) void k_bscan(const int* __restrict__ btot,
                                               int* __restrict__ bucket_ptr) {
    int t = threadIdx.x;
    int v = (t < NBUCKET) ? btot[t] : 0;
    __shared__ int part[256];
    part[t] = v;
    __syncthreads();
    for (int off = 1; off < 256; off <<= 1) {
        int x = (t >= off) ? part[t - off] : 0;
        __syncthreads();
        part[t] += x;
        __syncthreads();
    }
    if (t < NBUCKET) bucket_ptr[t] = part[t] - v;
    if (t == NBUCKET - 1) bucket_ptr[NBUCKET] = part[t];
}

// K2c: per-(chunk,bucket) exclusive offsets (scan over chunks for one bucket)
__global__ __launch_bounds__(256) void k_choff(const int* __restrict__ chunkhist,
                                               const int* __restrict__ bucket_ptr,
                                               int* __restrict__ chunkoff) {
    const int PER = (NCHUNK + 255) / 256;   // 4
    int b = blockIdx.x, t = threadIdx.x;
    int c0 = t * PER;
    int v[PER];
    int s = 0;
#pragma unroll
    for (int i = 0; i < PER; ++i) {
        int c = c0 + i;
        v[i] = (c < NCHUNK) ? chunkhist[c * NBUCKET + b] : 0;
        s += v[i];
    }
    __shared__ int part[256];
    part[t] = s;
    __syncthreads();
    for (int off = 1; off < 256; off <<= 1) {
        int x = (t >= off) ? part[t - off] : 0;
        __syncthreads();
        part[t] += x;
        __syncthreads();
    }
    int run = bucket_ptr[b] + part[t] - s;
#pragma unroll
    for (int i = 0; i < PER; ++i) {
        int c = c0 + i;
        if (c < NCHUNK) { chunkoff[c * NBUCKET + b] = run; run += v[i]; }
    }
}

// K3: scatter packed (src<<8 | dst&255) records into bucket runs (LDS cursors)
__global__ __launch_bounds__(256) void k_scatter(const int* __restrict__ src,
                                                 const int* __restrict__ dst,
                                                 const int* __restrict__ chunkoff,
                                                 int* __restrict__ packed) {
    __shared__ int cur[NBUCKET];
    int t = threadIdx.x, c = blockIdx.x;
    for (int i = t; i < NBUCKET; i += 256) cur[i] = chunkoff[c * NBUCKET + i];
    __syncthreads();
    int e0 = c * CHUNK;
    int cnt = min(CHUNK, N_EDGES - e0);
    for (int i = t; i < cnt; i += 256) {
        int d = dst[e0 + i], s = src[e0 + i];
        int pos = atomicAdd(&cur[d >> 8], 1);   // LDS atomic
        packed[pos] = (s << 8) | (d & 255);
    }
}

// K4: per-bucket fine hist + scan -> row_ptr, then scatter col_src in-window
__global__ __launch_bounds__(256) void k_finalize(const int* __restrict__ bucket_ptr,
                                                  const int* __restrict__ packed,
                                                  int* __restrict__ row_ptr,
                                                  int* __restrict__ col_src) {
    __shared__ int hist[256];
    __shared__ int part[256];
    __shared__ int cur[256];
    int b = blockIdx.x, t = threadIdx.x;
    hist[t] = 0;
    __syncthreads();
    int ebeg = bucket_ptr[b], eend = bucket_ptr[b + 1];
    int m = eend - ebeg;
    for (int i = t; i < m; i += 256)
        atomicAdd(&hist[packed[ebeg + i] & 255], 1);   // LDS atomic
    __syncthreads();
    int v = hist[t];
    part[t] = v;
    __syncthreads();
    for (int off = 1; off < 256; off <<= 1) {
        int x = (t >= off) ? part[t - off] : 0;
        __syncthreads();
        part[t] += x;
        __syncthreads();
    }
    int excl = part[t] - v;
    int node = b * 256 + t;
    if (node < N_NODES) row_ptr[node] = ebeg + excl;
    if (node == N_NODES - 1) row_ptr[N_NODES] = eend;
    cur[t] = ebeg + excl;
    __syncthreads();
    for (int i = t; i < m; i += 256) {
        int p = packed[ebeg + i];
        int pos = atomicAdd(&cur[p & 255], 1);   // LDS atomic
        col_src[pos] = p >> 8;
    }
}

// ================= Q/K/V projection (Q fp32, K/V bf16 out) ==================

__global__ __launch_bounds__(256) void proj_kernel(
    const float* __restrict__ h,
    const float* __restrict__ WQ, const float* __restrict__ WK, const float* __restrict__ WV,
    const float* __restrict__ bQ, const float* __restrict__ bK, const float* __restrict__ bV,
    float* __restrict__ Q, __hip_bfloat16* __restrict__ Kb, __hip_bfloat16* __restrict__ Vb) {
    __shared__ float hs[32][128];
    int t = threadIdx.x;
    int row0 = blockIdx.x * 32;
    for (int i = t; i < 32 * 128; i += 256) {
        int r = i >> 7, c = i & 127;
        int gr = row0 + r;
        hs[r][c] = (gr < N_NODES) ? h[gr * 128 + c] : 0.0f;
    }
    __syncthreads();
    int c = t & 127;
    int r0 = (t >> 7) * 16;
    float accQ[16], accK[16], accV[16];
#pragma unroll
    for (int r = 0; r < 16; ++r) { accQ[r] = 0.f; accK[r] = 0.f; accV[r] = 0.f; }
#pragma unroll 4
    for (int k = 0; k < 128; ++k) {
        float wq = WQ[k * 128 + c];
        float wk = WK[k * 128 + c];
        float wv = WV[k * 128 + c];
#pragma unroll
        for (int r = 0; r < 16; ++r) {
            float hv = hs[r0 + r][k];
            accQ[r] = fmaf(hv, wq, accQ[r]);
            accK[r] = fmaf(hv, wk, accK[r]);
            accV[r] = fmaf(hv, wv, accV[r]);
        }
    }
    float bq = bQ[c], bk = bK[c], bv = bV[c];
#pragma unroll
    for (int r = 0; r < 16; ++r) {
        int gr = row0 + r0 + r;
        if (gr < N_NODES) {
            Q[gr * 128 + c]  = accQ[r] + bq;
            Kb[gr * 128 + c] = __float2bfloat16(accK[r] + bk);
            Vb[gr * 128 + c] = __float2bfloat16(accV[r] + bv);
        }
    }
}

// ================= Gather attention (one wave / node, 4 edges in flight) ====

__device__ __forceinline__ float blo(unsigned u) { return __uint_as_float(u << 16); }
__device__ __forceinline__ float bhi(unsigned u) { return __uint_as_float(u & 0xffff0000u); }

__global__ __launch_bounds__(64) void attn_kernel(
    const float* __restrict__ Q,
    const __hip_bfloat16* __restrict__ Kb, const __hip_bfloat16* __restrict__ Vb,
    const int* __restrict__ row_ptr, const int* __restrict__ col_src,
    float* __restrict__ out) {
    int n = blockIdx.x;
    int t = threadIdx.x;
    int q4 = t >> 4;     // quarter 0..3
    int p  = t & 15;     // lane in quarter

    const float4* Qv = (const float4*)(Q + (size_t)n * 128 + p * 8);
    float4 qa = Qv[0], qb = Qv[1];

    int beg = row_ptr[n], end = row_ptr[n + 1];
    float acc[8];
#pragma unroll
    for (int d = 0; d < 8; ++d) acc[d] = 0.f;
    float z = 0.f;

    for (int base = beg; base < end; base += 64) {
        int mm = min(64, end - base);
        int e_l = col_src[(base + t < end) ? (base + t) : beg];
        int iters = (mm + 3) >> 2;
        for (int i = 0; i < iters; ++i) {
            int ei = 4 * i + q4;
            bool valid = ei < mm;
            int s = __shfl(e_l, ei);
            const uint4* Kv = (const uint4*)((const unsigned short*)Kb + (size_t)s * 128 + p * 8);
            uint4 kr = *Kv;
            const uint4* Vv = (const uint4*)((const unsigned short*)Vb + (size_t)s * 128 + p * 8);
            uint4 vr = *Vv;
            float dot = blo(kr.x) * qa.x + bhi(kr.x) * qa.y
                      + blo(kr.y) * qa.z + bhi(kr.y) * qa.w
                      + blo(kr.z) * qb.x + bhi(kr.z) * qb.y
                      + blo(kr.w) * qb.z + bhi(kr.w) * qb.w;
            dot += __shfl_xor(dot, 1);
            float sc = __expf(fminf(fmaxf(dot * 0.25f, -5.f), 5.f));
            if (!valid) sc = 0.f;
            acc[0] = fmaf(sc, blo(vr.x), acc[0]);
            acc[1] = fmaf(sc, bhi(vr.x), acc[1]);
            acc[2] = fmaf(sc, blo(vr.y), acc[2]);
            acc[3] = fmaf(sc, bhi(vr.y), acc[3]);
            acc[4] = fmaf(sc, blo(vr.z), acc[4]);
            acc[5] = fmaf(sc, bhi(vr.z), acc[5]);
            acc[6] = fmaf(sc, blo(vr.w), acc[6]);
            acc[7] = fmaf(sc, bhi(vr.w), acc[7]);
            z += sc;
        }
    }
#pragma unroll
    for (int d = 0; d < 8; ++d) {
        acc[d] += __shfl_xor(acc[d], 16);
        acc[d] += __shfl_xor(acc[d], 32);
    }
    z += __shfl_xor(z, 16);
    z += __shfl_xor(z, 32);

    if (q4 == 0) {
        float inv = 1.f / z;
        float4 o0 = {acc[0] * inv, acc[1] * inv, acc[2] * inv, acc[3] * inv};
        float4 o1 = {acc[4] * inv, acc[5] * inv, acc[6] * inv, acc[7] * inv};
        float4* O = (float4*)(out + (size_t)n * 128 + p * 8);
        O[0] = o0;
        O[1] = o1;
    }
}

// ================= launch ===================================================

extern "C" void kernel_launch(void* const* d_in, const int* in_sizes, int n_in,
                              void* d_out, int out_size, void* d_ws, size_t ws_size,
                              hipStream_t stream) {
    const float* h  = (const float*)d_in[0];
    const int*   src = (const int*)d_in[1];
    const int*   dst = (const int*)d_in[2];
    const float* WQ = (const float*)d_in[3];
    const float* WK = (const float*)d_in[4];
    const float* WV = (const float*)d_in[5];
    const float* bQ = (const float*)d_in[6];
    const float* bK = (const float*)d_in[7];
    const float* bV = (const float*)d_in[8];
    float* out = (float*)d_out;

    const size_t NH = (size_t)N_NODES * HD;
    float* Q = (float*)d_ws;
    __hip_bfloat16* Kb = (__hip_bfloat16*)(Q + NH);
    __hip_bfloat16* Vb = Kb + NH;
    int* row_ptr    = (int*)(Vb + NH);
    int* bucket_ptr = row_ptr + (N_NODES + 1);
    int* btot       = bucket_ptr + (NBUCKET + 1);
    int* chunkhist  = btot + NBUCKET;
    int* chunkoff   = chunkhist + (size_t)NCHUNK * NBUCKET;
    int* packed     = chunkoff + (size_t)NCHUNK * NBUCKET;
    int* col_src    = packed + N_EDGES;

    k_chunkhist<<<NCHUNK, 256, 0, stream>>>(dst, chunkhist);
    k_btot<<<NBUCKET, 256, 0, stream>>>(chunkhist, btot);
    k_bscan<<<1, 256, 0, stream>>>(btot, bucket_ptr);
    k_choff<<<NBUCKET, 256, 0, stream>>>(chunkhist, bucket_ptr, chunkoff);
    k_scatter<<<NCHUNK, 256, 0, stream>>>(src, dst, chunkoff, packed);
    k_finalize<<<NBUCKET, 256, 0, stream>>>(bucket_ptr, packed, row_ptr, col_src);
    proj_kernel<<<(N_NODES + 31) / 32, 256, 0, stream>>>(h, WQ, WK, WV, bQ, bK, bV, Q, Kb, Vb);
    attn_kernel<<<N_NODES, 64, 0, stream>>>(Q, Kb, Vb, row_ptr, col_src, out);
}

// Round 5
// 306.983 us; speedup vs baseline: 2.3000x; 1.0882x over previous
//
#include <hip/hip_runtime.h>

#define N_NODES 50000
#define N_PAD   50048                            // 782 * 64
#define N_EDGES 1600000
#define HD 128                                   // H*D = 8*16
#define CHUNK 2048
#define NCHUNK ((N_EDGES + CHUNK - 1) / CHUNK)   // 782
#define NBUCKET ((N_NODES + 127) / 128)          // 391 buckets of 128 nodes

typedef __attribute__((ext_vector_type(8))) short short8;   // 8 bf16
typedef __attribute__((ext_vector_type(4))) float floatx4;

union U4S8 { uint4 u; short8 s; };

// round-to-nearest-even float -> bf16 bits
__device__ __forceinline__ unsigned short f2bf(float f) {
    unsigned u = __float_as_uint(f);
    unsigned r = (u + 0x7fffu + ((u >> 16) & 1u)) >> 16;
    return (unsigned short)r;
}

// ================= prep: h -> bf16 (padded), W -> MFMA-fragment order =======
// hb blocks: tid over 8-elem groups of 50048x128. Wf blocks: 24 ntiles x 4
// ksteps x 64 lanes, 8 bf16 each. Wf[((ntile*4+kstep)*64+lane)*8+j] =
// W[g][k=kstep*32+(lane>>4)*8+j][c=(ntile&7)*16+(lane&15)], g=ntile>>3.
#define HB_BLOCKS ((N_PAD * HD / 8) / 256)       // 3128

__global__ __launch_bounds__(256) void prep_kernel(
    const float* __restrict__ h,
    const float* __restrict__ WQ, const float* __restrict__ WK, const float* __restrict__ WV,
    unsigned short* __restrict__ hb, unsigned short* __restrict__ Wf) {
    int bid = blockIdx.x, t = threadIdx.x;
    if (bid < HB_BLOCKS) {
        int tid = bid * 256 + t;                 // 8-elem group id
        int row = tid >> 4, c8 = tid & 15;
        uint4 outv;
        if (row < N_NODES) {
            const float4* src = (const float4*)(h + (size_t)row * HD + c8 * 8);
            float4 a = src[0], b = src[1];
            unsigned short r[8];
            r[0] = f2bf(a.x); r[1] = f2bf(a.y);
            r[2] = f2bf(a.z); r[3] = f2bf(a.w);
            r[4] = f2bf(b.x); r[5] = f2bf(b.y);
            r[6] = f2bf(b.z); r[7] = f2bf(b.w);
            outv = *(uint4*)r;
        } else {
            outv = make_uint4(0, 0, 0, 0);
        }
        *(uint4*)(hb + (size_t)tid * 8) = outv;
    } else {
        int tid = (bid - HB_BLOCKS) * 256 + t;   // 0..6143
        if (tid < 24 * 4 * 64) {
            int lane = tid & 63;
            int kstep = (tid >> 6) & 3;
            int ntile = tid >> 8;
            int g = ntile >> 3;
            int c = (ntile & 7) * 16 + (lane & 15);
            int k0 = kstep * 32 + (lane >> 4) * 8;
            const float* W = (g == 0) ? WQ : (g == 1) ? WK : WV;
            unsigned short r[8];
#pragma unroll
            for (int j = 0; j < 8; ++j)
                r[j] = f2bf(W[(size_t)(k0 + j) * HD + c]);
            *(uint4*)(Wf + (size_t)tid * 8) = *(uint4*)r;
        }
    }
}

// ================= CSR build (two-level counting sort, no global atomic rets)

__global__ __launch_bounds__(256) void k_chunkhist(const int* __restrict__ dst,
                                                   int* __restrict__ chunkhist,
                                                   int* __restrict__ btot) {
    __shared__ int hist[NBUCKET];
    int t = threadIdx.x, c = blockIdx.x;
    for (int i = t; i < NBUCKET; i += 256) hist[i] = 0;
    __syncthreads();
    int e0 = c * CHUNK;
    int cnt = min(CHUNK, N_EDGES - e0);
    for (int i = t; i < cnt; i += 256)
        atomicAdd(&hist[dst[e0 + i] >> 7], 1);
    __syncthreads();
    for (int i = t; i < NBUCKET; i += 256) {
        int v = hist[i];
        chunkhist[c * NBUCKET + i] = v;
        if (v) atomicAdd(&btot[i], v);           // fire-and-forget
    }
}

__global__ __launch_bounds__(512) void k_bscan(const int* __restrict__ btot,
                                               int* __restrict__ bucket_ptr) {
    int t = threadIdx.x;
    int v = (t < NBUCKET) ? btot[t] : 0;
    __shared__ int part[512];
    part[t] = v;
    __syncthreads();
    for (int off = 1; off < 512; off <<= 1) {
        int x = (t >= off) ? part[t - off] : 0;
        __syncthreads();
        part[t] += x;
        __syncthreads();
    }
    if (t < NBUCKET) bucket_ptr[t] = part[t] - v;
    if (t == NBUCKET - 1) bucket_ptr[NBUCKET] = part[t];
}

__global__ __launch_bounds__(256) void k_choff(const int* __restrict__ chunkhist,
                                               const int* __restrict__ bucket_ptr,
                                               int* __restrict__ chunkoff) {
    const int PER = (NCHUNK + 255) / 256;        // 4
    int b = blockIdx.x, t = threadIdx.x;
    int c0 = t * PER;
    int v[PER];
    int s = 0;
#pragma unroll
    for (int i = 0; i < PER; ++i) {
        int c = c0 + i;
        v[i] = (c < NCHUNK) ? chunkhist[c * NBUCKET + b] : 0;
        s += v[i];
    }
    __shared__ int part[256];
    part[t] = s;
    __syncthreads();
    for (int off = 1; off < 256; off <<= 1) {
        int x = (t >= off) ? part[t - off] : 0;
        __syncthreads();
        part[t] += x;
        __syncthreads();
    }
    int run = bucket_ptr[b] + part[t] - s;
#pragma unroll
    for (int i = 0; i < PER; ++i) {
        int c = c0 + i;
        if (c < NCHUNK) { chunkoff[c * NBUCKET + b] = run; run += v[i]; }
    }
}

__global__ __launch_bounds__(256) void k_scatter(const int* __restrict__ src,
                                                 const int* __restrict__ dst,
                                                 const int* __restrict__ chunkoff,
                                                 int* __restrict__ packed) {
    __shared__ int cur[NBUCKET];
    int t = threadIdx.x, c = blockIdx.x;
    for (int i = t; i < NBUCKET; i += 256) cur[i] = chunkoff[c * NBUCKET + i];
    __syncthreads();
    int e0 = c * CHUNK;
    int cnt = min(CHUNK, N_EDGES - e0);
    for (int i = t; i < cnt; i += 256) {
        int d = dst[e0 + i], s = src[e0 + i];
        int pos = atomicAdd(&cur[d >> 7], 1);    // LDS atomic
        packed[pos] = (s << 7) | (d & 127);
    }
}

__global__ __launch_bounds__(256) void k_finalize(const int* __restrict__ bucket_ptr,
                                                  const int* __restrict__ packed,
                                                  int* __restrict__ row_ptr,
                                                  int* __restrict__ col_src) {
    __shared__ int hist[128], part[128], cur[128];
    int b = blockIdx.x, t = threadIdx.x;
    if (t < 128) hist[t] = 0;
    __syncthreads();
    int ebeg = bucket_ptr[b], eend = bucket_ptr[b + 1];
    int m = eend - ebeg;
    for (int i = t; i < m; i += 256)
        atomicAdd(&hist[packed[ebeg + i] & 127], 1);
    __syncthreads();
    int v = 0;
    if (t < 128) { v = hist[t]; part[t] = v; }
    __syncthreads();
    for (int off = 1; off < 128; off <<= 1) {
        int x = 0;
        if (t < 128 && t >= off) x = part[t - off];
        __syncthreads();
        if (t < 128) part[t] += x;
        __syncthreads();
    }
    if (t < 128) {
        int excl = part[t] - v;
        int node = b * 128 + t;
        if (node < N_NODES) row_ptr[node] = ebeg + excl;
        if (node == N_NODES - 1) row_ptr[N_NODES] = eend;
        cur[t] = ebeg + excl;
    }
    __syncthreads();
    for (int i = t; i < m; i += 256) {
        int p = packed[ebeg + i];
        int pos = atomicAdd(&cur[p & 127], 1);
        col_src[pos] = p >> 7;
    }
}

// ================= proj: bf16 MFMA GEMM, C[M=50048][N=384] = hb @ [WQ|WK|WV]
// Block: 256 threads = 4 waves, M-tile 64. Wave w -> ntiles w*6..w*6+5.
// No LDS: A-frags straight from hb, B-frags from fragment-ordered Wf.

__global__ __launch_bounds__(256) void proj_mfma(
    const unsigned short* __restrict__ hb, const unsigned short* __restrict__ Wf,
    const float* __restrict__ bQ, const float* __restrict__ bK, const float* __restrict__ bV,
    float* __restrict__ Qo, unsigned short* __restrict__ Kb, unsigned short* __restrict__ Vb) {
    int t = threadIdx.x;
    int w = t >> 6;          // wave 0..3
    int l = t & 63;          // lane
    int m0 = blockIdx.x * 64;
    int nt0 = w * 6;         // first global ntile for this wave

    floatx4 acc[4][6];
#pragma unroll
    for (int mt = 0; mt < 4; ++mt)
#pragma unroll
        for (int nt = 0; nt < 6; ++nt)
            acc[mt][nt] = (floatx4){0.f, 0.f, 0.f, 0.f};

    int arow = m0 + (l & 15);           // +mt*16
    int akoff = (l >> 4) * 8;           // +kstep*32

#pragma unroll
    for (int kstep = 0; kstep < 4; ++kstep) {
        short8 a[4], b[6];
#pragma unroll
        for (int mt = 0; mt < 4; ++mt) {
            U4S8 u;
            u.u = *(const uint4*)(hb + (size_t)(arow + mt * 16) * HD + akoff + kstep * 32);
            a[mt] = u.s;
        }
#pragma unroll
        for (int nt = 0; nt < 6; ++nt) {
            U4S8 u;
            u.u = *(const uint4*)(Wf + ((size_t)((nt0 + nt) * 4 + kstep) * 64 + l) * 8);
            b[nt] = u.s;
        }
#pragma unroll
        for (int mt = 0; mt < 4; ++mt)
#pragma unroll
            for (int nt = 0; nt < 6; ++nt)
                acc[mt][nt] = __builtin_amdgcn_mfma_f32_16x16x32_bf16(
                    a[mt], b[nt], acc[mt][nt], 0, 0, 0);
    }

    // epilogue: row=(l>>4)*4+r (+mt*16+m0), col=(l&15) within ntile
#pragma unroll
    for (int nt = 0; nt < 6; ++nt) {
        int ntile = nt0 + nt;
        int g = ntile >> 3;
        int cc = (ntile & 7) * 16 + (l & 15);
        float bias = (g == 0) ? bQ[cc] : (g == 1) ? bK[cc] : bV[cc];
#pragma unroll
        for (int mt = 0; mt < 4; ++mt) {
#pragma unroll
            for (int r = 0; r < 4; ++r) {
                int grow = m0 + mt * 16 + (l >> 4) * 4 + r;
                if (grow < N_NODES) {
                    float val = acc[mt][nt][r] + bias;
                    if (g == 0)      Qo[(size_t)grow * HD + cc] = val;
                    else if (g == 1) Kb[(size_t)grow * HD + cc] = f2bf(val);
                    else             Vb[(size_t)grow * HD + cc] = f2bf(val);
                }
            }
        }
    }
}

// ================= attention: head-per-lane octets, 8 edges in flight =======

__device__ __forceinline__ float blo(unsigned u) { return __uint_as_float(u << 16); }
__device__ __forceinline__ float bhi(unsigned u) { return __uint_as_float(u & 0xffff0000u); }

__global__ __launch_bounds__(64) void attn_kernel(
    const float* __restrict__ Q,
    const unsigned short* __restrict__ Kb, const unsigned short* __restrict__ Vb,
    const int* __restrict__ row_ptr, const int* __restrict__ col_src,
    float* __restrict__ out) {
    int n = blockIdx.x;
    int t = threadIdx.x;
    int o = t >> 3;          // octet 0..7 (edge slot)
    int p = t & 7;           // head index

    const float4* Qv = (const float4*)(Q + (size_t)n * HD + p * 16);
    float4 q0 = Qv[0], q1 = Qv[1], q2 = Qv[2], q3 = Qv[3];

    float acc[16];
#pragma unroll
    for (int j = 0; j < 16; ++j) acc[j] = 0.f;
    float z = 0.f;

    int beg = row_ptr[n], end = row_ptr[n + 1];

    for (int base = beg; base < end; base += 64) {
        int mm = min(64, end - base);
        int e_l = col_src[(base + t < end) ? (base + t) : beg];
        int steps = (mm + 7) >> 3;

        int s0 = __shfl(e_l, o);
        const uint4* Kp = (const uint4*)(Kb + (size_t)s0 * HD + p * 16);
        const uint4* Vp = (const uint4*)(Vb + (size_t)s0 * HD + p * 16);
        uint4 ka = Kp[0], kb = Kp[1], va = Vp[0], vb = Vp[1];

        for (int i = 0; i < steps; ++i) {
            uint4 nka = ka, nkb = kb, nva = va, nvb = vb;
            if (i + 1 < steps) {
                int s1 = __shfl(e_l, 8 * (i + 1) + o);
                const uint4* Kn = (const uint4*)(Kb + (size_t)s1 * HD + p * 16);
                const uint4* Vn = (const uint4*)(Vb + (size_t)s1 * HD + p * 16);
                nka = Kn[0]; nkb = Kn[1]; nva = Vn[0]; nvb = Vn[1];
            }
            float dot = blo(ka.x) * q0.x + bhi(ka.x) * q0.y
                      + blo(ka.y) * q0.z + bhi(ka.y) * q0.w
                      + blo(ka.z) * q1.x + bhi(ka.z) * q1.y
                      + blo(ka.w) * q1.z + bhi(ka.w) * q1.w
                      + blo(kb.x) * q2.x + bhi(kb.x) * q2.y
                      + blo(kb.y) * q2.z + bhi(kb.y) * q2.w
                      + blo(kb.z) * q3.x + bhi(kb.z) * q3.y
                      + blo(kb.w) * q3.z + bhi(kb.w) * q3.w;
            float sc = __expf(fminf(fmaxf(dot * 0.25f, -5.f), 5.f));
            if (8 * i + o >= mm) sc = 0.f;
            acc[0]  = fmaf(sc, blo(va.x), acc[0]);
            acc[1]  = fmaf(sc, bhi(va.x), acc[1]);
            acc[2]  = fmaf(sc, blo(va.y), acc[2]);
            acc[3]  = fmaf(sc, bhi(va.y), acc[3]);
            acc[4]  = fmaf(sc, blo(va.z), acc[4]);
            acc[5]  = fmaf(sc, bhi(va.z), acc[5]);
            acc[6]  = fmaf(sc, blo(va.w), acc[6]);
            acc[7]  = fmaf(sc, bhi(va.w), acc[7]);
            acc[8]  = fmaf(sc, blo(vb.x), acc[8]);
            acc[9]  = fmaf(sc, bhi(vb.x), acc[9]);
            acc[10] = fmaf(sc, blo(vb.y), acc[10]);
            acc[11] = fmaf(sc, bhi(vb.y), acc[11]);
            acc[12] = fmaf(sc, blo(vb.z), acc[12]);
            acc[13] = fmaf(sc, bhi(vb.z), acc[13]);
            acc[14] = fmaf(sc, blo(vb.w), acc[14]);
            acc[15] = fmaf(sc, bhi(vb.w), acc[15]);
            z += sc;
            ka = nka; kb = nkb; va = nva; vb = nvb;
        }
    }

    // combine octets (each lane keeps its head p)
#pragma unroll
    for (int j = 0; j < 16; ++j) {
        acc[j] += __shfl_xor(acc[j], 8);
        acc[j] += __shfl_xor(acc[j], 16);
        acc[j] += __shfl_xor(acc[j], 32);
    }
    z += __shfl_xor(z, 8);
    z += __shfl_xor(z, 16);
    z += __shfl_xor(z, 32);

    if (o == 0) {
        float inv = 1.f / z;
        float4* O = (float4*)(out + (size_t)n * HD + p * 16);
        O[0] = (float4){acc[0] * inv,  acc[1] * inv,  acc[2] * inv,  acc[3] * inv};
        O[1] = (float4){acc[4] * inv,  acc[5] * inv,  acc[6] * inv,  acc[7] * inv};
        O[2] = (float4){acc[8] * inv,  acc[9] * inv,  acc[10] * inv, acc[11] * inv};
        O[3] = (float4){acc[12] * inv, acc[13] * inv, acc[14] * inv, acc[15] * inv};
    }
}

// ================= launch ===================================================

static inline char* align256(char* p) {
    return (char*)(((uintptr_t)p + 255) & ~(uintptr_t)255);
}

extern "C" void kernel_launch(void* const* d_in, const int* in_sizes, int n_in,
                              void* d_out, int out_size, void* d_ws, size_t ws_size,
                              hipStream_t stream) {
    const float* h  = (const float*)d_in[0];
    const int*   src = (const int*)d_in[1];
    const int*   dst = (const int*)d_in[2];
    const float* WQ = (const float*)d_in[3];
    const float* WK = (const float*)d_in[4];
    const float* WV = (const float*)d_in[5];
    const float* bQ = (const float*)d_in[6];
    const float* bK = (const float*)d_in[7];
    const float* bV = (const float*)d_in[8];
    float* out = (float*)d_out;

    char* p = (char*)d_ws;
    float* Q = (float*)p;                 p += (size_t)N_PAD * HD * 4;
    unsigned short* Kb = (unsigned short*)p; p += (size_t)N_PAD * HD * 2;
    unsigned short* Vb = (unsigned short*)p; p += (size_t)N_PAD * HD * 2;
    unsigned short* hb = (unsigned short*)p; p += (size_t)N_PAD * HD * 2;
    unsigned short* Wf = (unsigned short*)p; p += (size_t)24 * 4 * 64 * 8 * 2;
    p = align256(p);
    int* row_ptr    = (int*)p;            p += (N_NODES + 2) * 4;
    p = align256(p);
    int* bucket_ptr = (int*)p;            p += (NBUCKET + 1) * 4;
    p = align256(p);
    int* btot       = (int*)p;            p += NBUCKET * 4;
    p = align256(p);
    int* chunkhist  = (int*)p;            p += (size_t)NCHUNK * NBUCKET * 4;
    p = align256(p);
    int* chunkoff   = (int*)p;            p += (size_t)NCHUNK * NBUCKET * 4;
    p = align256(p);
    int* packed     = (int*)p;            p += (size_t)N_EDGES * 4;
    p = align256(p);
    int* col_src    = (int*)p;            p += (size_t)N_EDGES * 4;

    (void)hipMemsetAsync(btot, 0, NBUCKET * sizeof(int), stream);
    prep_kernel<<<HB_BLOCKS + 24, 256, 0, stream>>>(h, WQ, WK, WV, hb, Wf);
    k_chunkhist<<<NCHUNK, 256, 0, stream>>>(dst, chunkhist, btot);
    k_bscan<<<1, 512, 0, stream>>>(btot, bucket_ptr);
    k_choff<<<NBUCKET, 256, 0, stream>>>(chunkhist, bucket_ptr, chunkoff);
    k_scatter<<<NCHUNK, 256, 0, stream>>>(src, dst, chunkoff, packed);
    k_finalize<<<NBUCKET, 256, 0, stream>>>(bucket_ptr, packed, row_ptr, col_src);
    proj_mfma<<<N_PAD / 64, 256, 0, stream>>>(hb, Wf, bQ, bK, bV, Q, Kb, Vb);
    attn_kernel<<<N_NODES, 64, 0, stream>>>(Q, Kb, Vb, row_ptr, col_src, out);
}

// Round 6
// 292.655 us; speedup vs baseline: 2.4126x; 1.0490x over previous
//
#include <hip/hip_runtime.h>

#define N_NODES 50000
#define N_PAD   50048                            // 782 * 64
#define N_EDGES 1600000
#define HD 128                                   // H*D = 8*16
#define CHUNK 4096
#define NCHUNK ((N_EDGES + CHUNK - 1) / CHUNK)   // 391
#define NBUCKET ((N_NODES + 127) / 128)          // 391 buckets of 128 nodes

typedef __attribute__((ext_vector_type(8))) short short8;   // 8 bf16
typedef __attribute__((ext_vector_type(4))) float floatx4;

union U4S8 { uint4 u; short8 s; };

// round-to-nearest-even float -> bf16 bits
__device__ __forceinline__ unsigned short f2bf(float f) {
    unsigned u = __float_as_uint(f);
    unsigned r = (u + 0x7fffu + ((u >> 16) & 1u)) >> 16;
    return (unsigned short)r;
}

// ================= prep: W -> MFMA-fragment order bf16; zero btot ==========
// Wf[((ntile*4+kstep)*64+lane)*8+j] = W[g][k=kstep*32+(lane>>4)*8+j]
//                                      [c=(ntile&7)*16+(lane&15)], g=ntile>>3.
__global__ __launch_bounds__(256) void prep_kernel(
    const float* __restrict__ WQ, const float* __restrict__ WK, const float* __restrict__ WV,
    unsigned short* __restrict__ Wf, int* __restrict__ btot) {
    int bid = blockIdx.x, t = threadIdx.x;
    if (bid < 24) {
        int tid = bid * 256 + t;                 // 0..6143
        int lane = tid & 63;
        int kstep = (tid >> 6) & 3;
        int ntile = tid >> 8;
        int g = ntile >> 3;
        int c = (ntile & 7) * 16 + (lane & 15);
        int k0 = kstep * 32 + (lane >> 4) * 8;
        const float* W = (g == 0) ? WQ : (g == 1) ? WK : WV;
        unsigned short r[8];
#pragma unroll
        for (int j = 0; j < 8; ++j)
            r[j] = f2bf(W[(size_t)(k0 + j) * HD + c]);
        *(uint4*)(Wf + (size_t)tid * 8) = *(uint4*)r;
    } else {
        int i = (bid - 24) * 256 + t;
        if (i < NBUCKET) btot[i] = 0;
    }
}

// ================= CSR build (no global atomic returns) =====================

__global__ __launch_bounds__(256) void k_chunkhist(const int* __restrict__ dst,
                                                   int* __restrict__ chunkhist,
                                                   int* __restrict__ btot) {
    __shared__ int hist[NBUCKET];
    int t = threadIdx.x, c = blockIdx.x;
    for (int i = t; i < NBUCKET; i += 256) hist[i] = 0;
    __syncthreads();
    int e0 = c * CHUNK;
    int cnt = min(CHUNK, N_EDGES - e0);          // multiple of 4 always
    const uint4* d4 = (const uint4*)(dst + e0);
    int cnt4 = cnt >> 2;
    for (int i = t; i < cnt4; i += 256) {
        uint4 v = d4[i];
        atomicAdd(&hist[v.x >> 7], 1);
        atomicAdd(&hist[v.y >> 7], 1);
        atomicAdd(&hist[v.z >> 7], 1);
        atomicAdd(&hist[v.w >> 7], 1);
    }
    __syncthreads();
    for (int i = t; i < NBUCKET; i += 256) {
        int v = hist[i];
        chunkhist[c * NBUCKET + i] = v;
        if (v) atomicAdd(&btot[i], v);           // fire-and-forget
    }
}

// per-(chunk,bucket) offsets; bucket base computed in-block (fused scan)
__global__ __launch_bounds__(256) void k_choff(const int* __restrict__ chunkhist,
                                               const int* __restrict__ btot,
                                               int* __restrict__ bucket_ptr,
                                               int* __restrict__ chunkoff) {
    int b = blockIdx.x, t = threadIdx.x;
    // base = sum btot[0..b-1]
    int x = 0;
    for (int i = t; i < NBUCKET; i += 256)
        if (i < b) x += btot[i];
    __shared__ int red[256];
    red[t] = x;
    __syncthreads();
    for (int off = 128; off > 0; off >>= 1) {
        if (t < off) red[t] += red[t + off];
        __syncthreads();
    }
    int base = red[0];
    if (t == 0) {
        bucket_ptr[b] = base;
        if (b == NBUCKET - 1) bucket_ptr[NBUCKET] = base + btot[b];
    }
    // scan chunk contributions for bucket b (PER=2 chunks per thread)
    const int PER = (NCHUNK + 255) / 256;        // 2
    int c0 = t * PER;
    int v[PER];
    int s = 0;
#pragma unroll
    for (int i = 0; i < PER; ++i) {
        int c = c0 + i;
        v[i] = (c < NCHUNK) ? chunkhist[c * NBUCKET + b] : 0;
        s += v[i];
    }
    __shared__ int part[256];
    part[t] = s;
    __syncthreads();
    for (int off = 1; off < 256; off <<= 1) {
        int y = (t >= off) ? part[t - off] : 0;
        __syncthreads();
        part[t] += y;
        __syncthreads();
    }
    int run = base + part[t] - s;
#pragma unroll
    for (int i = 0; i < PER; ++i) {
        int c = c0 + i;
        if (c < NCHUNK) { chunkoff[c * NBUCKET + b] = run; run += v[i]; }
    }
}

__global__ __launch_bounds__(256) void k_scatter(const int* __restrict__ src,
                                                 const int* __restrict__ dst,
                                                 const int* __restrict__ chunkoff,
                                                 int* __restrict__ packed) {
    __shared__ int cur[NBUCKET];
    int t = threadIdx.x, c = blockIdx.x;
    for (int i = t; i < NBUCKET; i += 256) cur[i] = chunkoff[c * NBUCKET + i];
    __syncthreads();
    int e0 = c * CHUNK;
    int cnt = min(CHUNK, N_EDGES - e0);
    const uint4* d4 = (const uint4*)(dst + e0);
    const uint4* s4 = (const uint4*)(src + e0);
    int cnt4 = cnt >> 2;
    for (int i = t; i < cnt4; i += 256) {
        uint4 d = d4[i];
        uint4 s = s4[i];
        int pos;
        pos = atomicAdd(&cur[d.x >> 7], 1); packed[pos] = (s.x << 7) | (d.x & 127);
        pos = atomicAdd(&cur[d.y >> 7], 1); packed[pos] = (s.y << 7) | (d.y & 127);
        pos = atomicAdd(&cur[d.z >> 7], 1); packed[pos] = (s.z << 7) | (d.z & 127);
        pos = atomicAdd(&cur[d.w >> 7], 1); packed[pos] = (s.w << 7) | (d.w & 127);
    }
}

__global__ __launch_bounds__(256) void k_finalize(const int* __restrict__ bucket_ptr,
                                                  const int* __restrict__ packed,
                                                  int* __restrict__ row_ptr,
                                                  int* __restrict__ col_src) {
    __shared__ int hist[128], part[128], cur[128];
    int b = blockIdx.x, t = threadIdx.x;
    if (t < 128) hist[t] = 0;
    __syncthreads();
    int ebeg = bucket_ptr[b], eend = bucket_ptr[b + 1];
    int m = eend - ebeg;
    for (int i = t; i < m; i += 256)
        atomicAdd(&hist[packed[ebeg + i] & 127], 1);
    __syncthreads();
    int v = 0;
    if (t < 128) { v = hist[t]; part[t] = v; }
    __syncthreads();
    for (int off = 1; off < 128; off <<= 1) {
        int x = 0;
        if (t < 128 && t >= off) x = part[t - off];
        __syncthreads();
        if (t < 128) part[t] += x;
        __syncthreads();
    }
    if (t < 128) {
        int excl = part[t] - v;
        int node = b * 128 + t;
        if (node < N_NODES) row_ptr[node] = ebeg + excl;
        if (node == N_NODES - 1) row_ptr[N_NODES] = eend;
        cur[t] = ebeg + excl;
    }
    __syncthreads();
    for (int i = t; i < m; i += 256) {
        int p = packed[ebeg + i];
        int pos = atomicAdd(&cur[p & 127], 1);
        col_src[pos] = p >> 7;
    }
}

// ================= proj: bf16 MFMA GEMM, reads h fp32 directly ==============
// Block: 256 threads = 4 waves, M-tile 64. Wave w -> ntiles w*6..w*6+5.

__global__ __launch_bounds__(256) void proj_mfma(
    const float* __restrict__ h, const unsigned short* __restrict__ Wf,
    const float* __restrict__ bQ, const float* __restrict__ bK, const float* __restrict__ bV,
    float* __restrict__ Qo, unsigned short* __restrict__ Kb, unsigned short* __restrict__ Vb) {
    int t = threadIdx.x;
    int w = t >> 6;          // wave 0..3
    int l = t & 63;          // lane
    int m0 = blockIdx.x * 64;
    int nt0 = w * 6;         // first global ntile for this wave

    floatx4 acc[4][6];
#pragma unroll
    for (int mt = 0; mt < 4; ++mt)
#pragma unroll
        for (int nt = 0; nt < 6; ++nt)
            acc[mt][nt] = (floatx4){0.f, 0.f, 0.f, 0.f};

    int arow = m0 + (l & 15);           // +mt*16
    int akoff = (l >> 4) * 8;           // +kstep*32

#pragma unroll
    for (int kstep = 0; kstep < 4; ++kstep) {
        short8 a[4], b[6];
#pragma unroll
        for (int mt = 0; mt < 4; ++mt) {
            int row = arow + mt * 16;
            unsigned short r[8];
            if (row < N_NODES) {
                const float4* ap = (const float4*)(h + (size_t)row * HD + akoff + kstep * 32);
                float4 f0 = ap[0], f1 = ap[1];
                r[0] = f2bf(f0.x); r[1] = f2bf(f0.y); r[2] = f2bf(f0.z); r[3] = f2bf(f0.w);
                r[4] = f2bf(f1.x); r[5] = f2bf(f1.y); r[6] = f2bf(f1.z); r[7] = f2bf(f1.w);
            } else {
#pragma unroll
                for (int j = 0; j < 8; ++j) r[j] = 0;
            }
            a[mt] = *(short8*)r;
        }
#pragma unroll
        for (int nt = 0; nt < 6; ++nt) {
            U4S8 u;
            u.u = *(const uint4*)(Wf + ((size_t)((nt0 + nt) * 4 + kstep) * 64 + l) * 8);
            b[nt] = u.s;
        }
#pragma unroll
        for (int mt = 0; mt < 4; ++mt)
#pragma unroll
            for (int nt = 0; nt < 6; ++nt)
                acc[mt][nt] = __builtin_amdgcn_mfma_f32_16x16x32_bf16(
                    a[mt], b[nt], acc[mt][nt], 0, 0, 0);
    }

    // epilogue: row=(l>>4)*4+r (+mt*16+m0), col=(l&15) within ntile
#pragma unroll
    for (int nt = 0; nt < 6; ++nt) {
        int ntile = nt0 + nt;
        int g = ntile >> 3;
        int cc = (ntile & 7) * 16 + (l & 15);
        float bias = (g == 0) ? bQ[cc] : (g == 1) ? bK[cc] : bV[cc];
#pragma unroll
        for (int mt = 0; mt < 4; ++mt) {
#pragma unroll
            for (int r = 0; r < 4; ++r) {
                int grow = m0 + mt * 16 + (l >> 4) * 4 + r;
                if (grow < N_NODES) {
                    float val = acc[mt][nt][r] + bias;
                    if (g == 0)      Qo[(size_t)grow * HD + cc] = val;
                    else if (g == 1) Kb[(size_t)grow * HD + cc] = f2bf(val);
                    else             Vb[(size_t)grow * HD + cc] = f2bf(val);
                }
            }
        }
    }
}

// ================= attention: 4 nodes per 256-thread block ==================
// Per wave: head-per-lane octets, 8 edges in flight, 2-deep pipeline.

__device__ __forceinline__ float blo(unsigned u) { return __uint_as_float(u << 16); }
__device__ __forceinline__ float bhi(unsigned u) { return __uint_as_float(u & 0xffff0000u); }

__global__ __launch_bounds__(256) void attn_kernel(
    const float* __restrict__ Q,
    const unsigned short* __restrict__ Kb, const unsigned short* __restrict__ Vb,
    const int* __restrict__ row_ptr, const int* __restrict__ col_src,
    float* __restrict__ out) {
    int n = blockIdx.x * 4 + (threadIdx.x >> 6);
    if (n >= N_NODES) return;
    int l = threadIdx.x & 63;
    int o = l >> 3;          // octet 0..7 (edge slot)
    int p = l & 7;           // head index

    const float4* Qv = (const float4*)(Q + (size_t)n * HD + p * 16);
    float4 q0 = Qv[0], q1 = Qv[1], q2 = Qv[2], q3 = Qv[3];

    float acc[16];
#pragma unroll
    for (int j = 0; j < 16; ++j) acc[j] = 0.f;
    float z = 0.f;

    int beg = row_ptr[n], end = row_ptr[n + 1];

    for (int base = beg; base < end; base += 64) {
        int mm = min(64, end - base);
        int e_l = col_src[(base + l < end) ? (base + l) : beg];
        int steps = (mm + 7) >> 3;

        int s0 = __shfl(e_l, o);
        const uint4* Kp = (const uint4*)(Kb + (size_t)s0 * HD + p * 16);
        const uint4* Vp = (const uint4*)(Vb + (size_t)s0 * HD + p * 16);
        uint4 ka = Kp[0], kb = Kp[1], va = Vp[0], vb = Vp[1];

        for (int i = 0; i < steps; ++i) {
            uint4 nka = ka, nkb = kb, nva = va, nvb = vb;
            if (i + 1 < steps) {
                int s1 = __shfl(e_l, 8 * (i + 1) + o);
                const uint4* Kn = (const uint4*)(Kb + (size_t)s1 * HD + p * 16);
                const uint4* Vn = (const uint4*)(Vb + (size_t)s1 * HD + p * 16);
                nka = Kn[0]; nkb = Kn[1]; nva = Vn[0]; nvb = Vn[1];
            }
            float dot = blo(ka.x) * q0.x + bhi(ka.x) * q0.y
                      + blo(ka.y) * q0.z + bhi(ka.y) * q0.w
                      + blo(ka.z) * q1.x + bhi(ka.z) * q1.y
                      + blo(ka.w) * q1.z + bhi(ka.w) * q1.w
                      + blo(kb.x) * q2.x + bhi(kb.x) * q2.y
                      + blo(kb.y) * q2.z + bhi(kb.y) * q2.w
                      + blo(kb.z) * q3.x + bhi(kb.z) * q3.y
                      + blo(kb.w) * q3.z + bhi(kb.w) * q3.w;
            float sc = __expf(fminf(fmaxf(dot * 0.25f, -5.f), 5.f));
            if (8 * i + o >= mm) sc = 0.f;
            acc[0]  = fmaf(sc, blo(va.x), acc[0]);
            acc[1]  = fmaf(sc, bhi(va.x), acc[1]);
            acc[2]  = fmaf(sc, blo(va.y), acc[2]);
            acc[3]  = fmaf(sc, bhi(va.y), acc[3]);
            acc[4]  = fmaf(sc, blo(va.z), acc[4]);
            acc[5]  = fmaf(sc, bhi(va.z), acc[5]);
            acc[6]  = fmaf(sc, blo(va.w), acc[6]);
            acc[7]  = fmaf(sc, bhi(va.w), acc[7]);
            acc[8]  = fmaf(sc, blo(vb.x), acc[8]);
            acc[9]  = fmaf(sc, bhi(vb.x), acc[9]);
            acc[10] = fmaf(sc, blo(vb.y), acc[10]);
            acc[11] = fmaf(sc, bhi(vb.y), acc[11]);
            acc[12] = fmaf(sc, blo(vb.z), acc[12]);
            acc[13] = fmaf(sc, bhi(vb.z), acc[13]);
            acc[14] = fmaf(sc, blo(vb.w), acc[14]);
            acc[15] = fmaf(sc, bhi(vb.w), acc[15]);
            z += sc;
            ka = nka; kb = nkb; va = nva; vb = nvb;
        }
    }

    // combine octets (each lane keeps its head p)
#pragma unroll
    for (int j = 0; j < 16; ++j) {
        acc[j] += __shfl_xor(acc[j], 8);
        acc[j] += __shfl_xor(acc[j], 16);
        acc[j] += __shfl_xor(acc[j], 32);
    }
    z += __shfl_xor(z, 8);
    z += __shfl_xor(z, 16);
    z += __shfl_xor(z, 32);

    if (o == 0) {
        float inv = 1.f / z;
        float4* O = (float4*)(out + (size_t)n * HD + p * 16);
        O[0] = (float4){acc[0] * inv,  acc[1] * inv,  acc[2] * inv,  acc[3] * inv};
        O[1] = (float4){acc[4] * inv,  acc[5] * inv,  acc[6] * inv,  acc[7] * inv};
        O[2] = (float4){acc[8] * inv,  acc[9] * inv,  acc[10] * inv, acc[11] * inv};
        O[3] = (float4){acc[12] * inv, acc[13] * inv, acc[14] * inv, acc[15] * inv};
    }
}

// ================= launch ===================================================

static inline char* align256(char* p) {
    return (char*)(((uintptr_t)p + 255) & ~(uintptr_t)255);
}

extern "C" void kernel_launch(void* const* d_in, const int* in_sizes, int n_in,
                              void* d_out, int out_size, void* d_ws, size_t ws_size,
                              hipStream_t stream) {
    const float* h  = (const float*)d_in[0];
    const int*   src = (const int*)d_in[1];
    const int*   dst = (const int*)d_in[2];
    const float* WQ = (const float*)d_in[3];
    const float* WK = (const float*)d_in[4];
    const float* WV = (const float*)d_in[5];
    const float* bQ = (const float*)d_in[6];
    const float* bK = (const float*)d_in[7];
    const float* bV = (const float*)d_in[8];
    float* out = (float*)d_out;

    char* p = (char*)d_ws;
    float* Q = (float*)p;                    p += (size_t)N_PAD * HD * 4;
    unsigned short* Kb = (unsigned short*)p; p += (size_t)N_PAD * HD * 2;
    unsigned short* Vb = (unsigned short*)p; p += (size_t)N_PAD * HD * 2;
    unsigned short* Wf = (unsigned short*)p; p += (size_t)24 * 4 * 64 * 8 * 2;
    p = align256(p);
    int* row_ptr    = (int*)p;               p += (N_NODES + 2) * 4;
    p = align256(p);
    int* bucket_ptr = (int*)p;               p += (NBUCKET + 1) * 4;
    p = align256(p);
    int* btot       = (int*)p;               p += NBUCKET * 4;
    p = align256(p);
    int* chunkhist  = (int*)p;               p += (size_t)NCHUNK * NBUCKET * 4;
    p = align256(p);
    int* chunkoff   = (int*)p;               p += (size_t)NCHUNK * NBUCKET * 4;
    p = align256(p);
    int* packed     = (int*)p;               p += (size_t)N_EDGES * 4;
    p = align256(p);
    int* col_src    = (int*)p;               p += (size_t)N_EDGES * 4;

    prep_kernel<<<26, 256, 0, stream>>>(WQ, WK, WV, Wf, btot);
    k_chunkhist<<<NCHUNK, 256, 0, stream>>>(dst, chunkhist, btot);
    k_choff<<<NBUCKET, 256, 0, stream>>>(chunkhist, btot, bucket_ptr, chunkoff);
    k_scatter<<<NCHUNK, 256, 0, stream>>>(src, dst, chunkoff, packed);
    k_finalize<<<NBUCKET, 256, 0, stream>>>(bucket_ptr, packed, row_ptr, col_src);
    proj_mfma<<<N_PAD / 64, 256, 0, stream>>>(h, Wf, bQ, bK, bV, Q, Kb, Vb);
    attn_kernel<<<(N_NODES + 3) / 4, 256, 0, stream>>>(Q, Kb, Vb, row_ptr, col_src, out);
}

// Round 7
// 269.506 us; speedup vs baseline: 2.6198x; 1.0859x over previous
//
#include <hip/hip_runtime.h>

#define N_NODES 50000
#define N_PAD   50048                            // 782 * 64
#define N_EDGES 1600000
#define HD 128                                   // H*D = 8*16
#define CHUNK 4096
#define NCHUNK ((N_EDGES + CHUNK - 1) / CHUNK)   // 391
#define NBUCKET ((N_NODES + 127) / 128)          // 391 buckets of 128 nodes

typedef __attribute__((ext_vector_type(8))) short short8;   // 8 bf16
typedef __attribute__((ext_vector_type(4))) float floatx4;

union U4S8 { uint4 u; short8 s; };

// round-to-nearest-even float -> bf16 bits
__device__ __forceinline__ unsigned short f2bf(float f) {
    unsigned u = __float_as_uint(f);
    unsigned r = (u + 0x7fffu + ((u >> 16) & 1u)) >> 16;
    return (unsigned short)r;
}

// ================= chunkhist + W-prep (fused grid) ==========================
// blocks [0,NCHUNK): per-chunk histogram of dst>>7 + btot atomics.
// blocks [NCHUNK,NCHUNK+24): W -> MFMA-fragment-order bf16 Wf.
// Wf[((ntile*4+kstep)*64+lane)*8+j] = W[g][k=kstep*32+(lane>>4)*8+j]
//                                      [c=(ntile&7)*16+(lane&15)], g=ntile>>3.
__global__ __launch_bounds__(256) void k_chunkhist(
    const int* __restrict__ dst, int* __restrict__ chunkhist, int* __restrict__ btot,
    const float* __restrict__ WQ, const float* __restrict__ WK, const float* __restrict__ WV,
    unsigned short* __restrict__ Wf) {
    int t = threadIdx.x, c = blockIdx.x;
    if (c >= NCHUNK) {
        int tid = (c - NCHUNK) * 256 + t;        // 0..6143
        int lane = tid & 63;
        int kstep = (tid >> 6) & 3;
        int ntile = tid >> 8;
        int g = ntile >> 3;
        int col = (ntile & 7) * 16 + (lane & 15);
        int k0 = kstep * 32 + (lane >> 4) * 8;
        const float* W = (g == 0) ? WQ : (g == 1) ? WK : WV;
        unsigned short r[8];
#pragma unroll
        for (int j = 0; j < 8; ++j)
            r[j] = f2bf(W[(size_t)(k0 + j) * HD + col]);
        *(uint4*)(Wf + (size_t)tid * 8) = *(uint4*)r;
        return;
    }
    __shared__ int hist[NBUCKET];
    for (int i = t; i < NBUCKET; i += 256) hist[i] = 0;
    __syncthreads();
    int e0 = c * CHUNK;
    int cnt = min(CHUNK, N_EDGES - e0);
    const uint4* d4 = (const uint4*)(dst + e0);
    int cnt4 = cnt >> 2;
    for (int i = t; i < cnt4; i += 256) {
        uint4 v = d4[i];
        atomicAdd(&hist[v.x >> 7], 1);
        atomicAdd(&hist[v.y >> 7], 1);
        atomicAdd(&hist[v.z >> 7], 1);
        atomicAdd(&hist[v.w >> 7], 1);
    }
    __syncthreads();
    for (int i = t; i < NBUCKET; i += 256) {
        int v = hist[i];
        chunkhist[c * NBUCKET + i] = v;
        if (v) atomicAdd(&btot[i], v);           // fire-and-forget
    }
}

// per-(chunk,bucket) offsets; bucket base computed in-block (fused scan)
__global__ __launch_bounds__(256) void k_choff(const int* __restrict__ chunkhist,
                                               const int* __restrict__ btot,
                                               int* __restrict__ bucket_ptr,
                                               int* __restrict__ chunkoff) {
    int b = blockIdx.x, t = threadIdx.x;
    int x = 0;
    for (int i = t; i < NBUCKET; i += 256)
        if (i < b) x += btot[i];
    __shared__ int red[256];
    red[t] = x;
    __syncthreads();
    for (int off = 128; off > 0; off >>= 1) {
        if (t < off) red[t] += red[t + off];
        __syncthreads();
    }
    int base = red[0];
    if (t == 0) {
        bucket_ptr[b] = base;
        if (b == NBUCKET - 1) bucket_ptr[NBUCKET] = base + btot[b];
    }
    const int PER = (NCHUNK + 255) / 256;        // 2
    int c0 = t * PER;
    int v[PER];
    int s = 0;
#pragma unroll
    for (int i = 0; i < PER; ++i) {
        int c = c0 + i;
        v[i] = (c < NCHUNK) ? chunkhist[c * NBUCKET + b] : 0;
        s += v[i];
    }
    __shared__ int part[256];
    part[t] = s;
    __syncthreads();
    for (int off = 1; off < 256; off <<= 1) {
        int y = (t >= off) ? part[t - off] : 0;
        __syncthreads();
        part[t] += y;
        __syncthreads();
    }
    int run = base + part[t] - s;
#pragma unroll
    for (int i = 0; i < PER; ++i) {
        int c = c0 + i;
        if (c < NCHUNK) { chunkoff[c * NBUCKET + b] = run; run += v[i]; }
    }
}

__global__ __launch_bounds__(256) void k_scatter(const int* __restrict__ src,
                                                 const int* __restrict__ dst,
                                                 const int* __restrict__ chunkoff,
                                                 int* __restrict__ packed) {
    __shared__ int cur[NBUCKET];
    int t = threadIdx.x, c = blockIdx.x;
    for (int i = t; i < NBUCKET; i += 256) cur[i] = chunkoff[c * NBUCKET + i];
    __syncthreads();
    int e0 = c * CHUNK;
    int cnt = min(CHUNK, N_EDGES - e0);
    const uint4* d4 = (const uint4*)(dst + e0);
    const uint4* s4 = (const uint4*)(src + e0);
    int cnt4 = cnt >> 2;
    for (int i = t; i < cnt4; i += 256) {
        uint4 d = d4[i];
        uint4 s = s4[i];
        int pos;
        pos = atomicAdd(&cur[d.x >> 7], 1); packed[pos] = (s.x << 7) | (d.x & 127);
        pos = atomicAdd(&cur[d.y >> 7], 1); packed[pos] = (s.y << 7) | (d.y & 127);
        pos = atomicAdd(&cur[d.z >> 7], 1); packed[pos] = (s.z << 7) | (d.z & 127);
        pos = atomicAdd(&cur[d.w >> 7], 1); packed[pos] = (s.w << 7) | (d.w & 127);
    }
}

__global__ __launch_bounds__(256) void k_finalize(const int* __restrict__ bucket_ptr,
                                                  const int* __restrict__ packed,
                                                  int* __restrict__ row_ptr,
                                                  int* __restrict__ col_src) {
    __shared__ int hist[128], part[128], cur[128];
    int b = blockIdx.x, t = threadIdx.x;
    if (t < 128) hist[t] = 0;
    __syncthreads();
    int ebeg = bucket_ptr[b], eend = bucket_ptr[b + 1];
    int m = eend - ebeg;
    for (int i = t; i < m; i += 256)
        atomicAdd(&hist[packed[ebeg + i] & 127], 1);
    __syncthreads();
    int v = 0;
    if (t < 128) { v = hist[t]; part[t] = v; }
    __syncthreads();
    for (int off = 1; off < 128; off <<= 1) {
        int x = 0;
        if (t < 128 && t >= off) x = part[t - off];
        __syncthreads();
        if (t < 128) part[t] += x;
        __syncthreads();
    }
    if (t < 128) {
        int excl = part[t] - v;
        int node = b * 128 + t;
        if (node < N_NODES) row_ptr[node] = ebeg + excl;
        if (node == N_NODES - 1) row_ptr[N_NODES] = eend;
        cur[t] = ebeg + excl;
    }
    __syncthreads();
    for (int i = t; i < m; i += 256) {
        int p = packed[ebeg + i];
        int pos = atomicAdd(&cur[p & 127], 1);
        col_src[pos] = p >> 7;
    }
}

// ================= proj: bf16 MFMA GEMM, wave-owns-16-rows ==================
// Block 256 = 4 waves; wave w owns rows [blk*64+w*16, +16), loops all 24
// ntiles with a single 4-VGPR acc live at a time. h read exactly once.

__global__ __launch_bounds__(256) void proj_mfma(
    const float* __restrict__ h, const unsigned short* __restrict__ Wf,
    const float* __restrict__ bQ, const float* __restrict__ bK, const float* __restrict__ bV,
    float* __restrict__ Qo, unsigned short* __restrict__ Kb, unsigned short* __restrict__ Vb) {
    int t = threadIdx.x;
    int w = t >> 6;          // wave 0..3
    int l = t & 63;          // lane
    int row0 = blockIdx.x * 64 + w * 16;
    int arow = row0 + (l & 15);
    int akoff = (l >> 4) * 8;
    bool rowok = arow < N_NODES;

    short8 a[4];
#pragma unroll
    for (int ks = 0; ks < 4; ++ks) {
        unsigned short r[8];
        if (rowok) {
            const float4* ap = (const float4*)(h + (size_t)arow * HD + ks * 32 + akoff);
            float4 f0 = ap[0], f1 = ap[1];
            r[0] = f2bf(f0.x); r[1] = f2bf(f0.y); r[2] = f2bf(f0.z); r[3] = f2bf(f0.w);
            r[4] = f2bf(f1.x); r[5] = f2bf(f1.y); r[6] = f2bf(f1.z); r[7] = f2bf(f1.w);
        } else {
#pragma unroll
            for (int j = 0; j < 8; ++j) r[j] = 0;
        }
        a[ks] = *(short8*)r;
    }

    int orow0 = row0 + (l >> 4) * 4;   // output rows orow0..orow0+3
#pragma unroll
    for (int nt = 0; nt < 24; ++nt) {
        floatx4 acc = (floatx4){0.f, 0.f, 0.f, 0.f};
#pragma unroll
        for (int ks = 0; ks < 4; ++ks) {
            U4S8 u;
            u.u = *(const uint4*)(Wf + ((size_t)(nt * 4 + ks) * 64 + l) * 8);
            acc = __builtin_amdgcn_mfma_f32_16x16x32_bf16(a[ks], u.s, acc, 0, 0, 0);
        }
        int g = nt >> 3;
        int cc = (nt & 7) * 16 + (l & 15);
        float bias = (g == 0) ? bQ[cc] : (g == 1) ? bK[cc] : bV[cc];
#pragma unroll
        for (int r = 0; r < 4; ++r) {
            int grow = orow0 + r;
            if (grow < N_NODES) {
                float val = acc[r] + bias;
                if (g == 0)      Qo[(size_t)grow * HD + cc] = val;
                else if (g == 1) Kb[(size_t)grow * HD + cc] = f2bf(val);
                else             Vb[(size_t)grow * HD + cc] = f2bf(val);
            }
        }
    }
}

// ================= attention: 4 nodes/block, node-range split ===============

__device__ __forceinline__ float blo(unsigned u) { return __uint_as_float(u << 16); }
__device__ __forceinline__ float bhi(unsigned u) { return __uint_as_float(u & 0xffff0000u); }

__global__ __launch_bounds__(256) void attn_kernel(
    const float* __restrict__ Q,
    const unsigned short* __restrict__ Kb, const unsigned short* __restrict__ Vb,
    const int* __restrict__ row_ptr, const int* __restrict__ col_src,
    float* __restrict__ out, int nbase, int nend) {
    int n = nbase + blockIdx.x * 4 + (threadIdx.x >> 6);
    if (n >= nend) return;
    int l = threadIdx.x & 63;
    int o = l >> 3;          // octet 0..7 (edge slot)
    int p = l & 7;           // head index

    const float4* Qv = (const float4*)(Q + (size_t)n * HD + p * 16);
    float4 q0 = Qv[0], q1 = Qv[1], q2 = Qv[2], q3 = Qv[3];

    float acc[16];
#pragma unroll
    for (int j = 0; j < 16; ++j) acc[j] = 0.f;
    float z = 0.f;

    int beg = row_ptr[n], end = row_ptr[n + 1];

    for (int base = beg; base < end; base += 64) {
        int mm = min(64, end - base);
        int e_l = col_src[(base + l < end) ? (base + l) : beg];
        int steps = (mm + 7) >> 3;

        int s0 = __shfl(e_l, o);
        const uint4* Kp = (const uint4*)(Kb + (size_t)s0 * HD + p * 16);
        const uint4* Vp = (const uint4*)(Vb + (size_t)s0 * HD + p * 16);
        uint4 ka = Kp[0], kb = Kp[1], va = Vp[0], vb = Vp[1];

        for (int i = 0; i < steps; ++i) {
            uint4 nka = ka, nkb = kb, nva = va, nvb = vb;
            if (i + 1 < steps) {
                int s1 = __shfl(e_l, 8 * (i + 1) + o);
                const uint4* Kn = (const uint4*)(Kb + (size_t)s1 * HD + p * 16);
                const uint4* Vn = (const uint4*)(Vb + (size_t)s1 * HD + p * 16);
                nka = Kn[0]; nkb = Kn[1]; nva = Vn[0]; nvb = Vn[1];
            }
            float dot = blo(ka.x) * q0.x + bhi(ka.x) * q0.y
                      + blo(ka.y) * q0.z + bhi(ka.y) * q0.w
                      + blo(ka.z) * q1.x + bhi(ka.z) * q1.y
                      + blo(ka.w) * q1.z + bhi(ka.w) * q1.w
                      + blo(kb.x) * q2.x + bhi(kb.x) * q2.y
                      + blo(kb.y) * q2.z + bhi(kb.y) * q2.w
                      + blo(kb.z) * q3.x + bhi(kb.z) * q3.y
                      + blo(kb.w) * q3.z + bhi(kb.w) * q3.w;
            float sc = __expf(fminf(fmaxf(dot * 0.25f, -5.f), 5.f));
            if (8 * i + o >= mm) sc = 0.f;
            acc[0]  = fmaf(sc, blo(va.x), acc[0]);
            acc[1]  = fmaf(sc, bhi(va.x), acc[1]);
            acc[2]  = fmaf(sc, blo(va.y), acc[2]);
            acc[3]  = fmaf(sc, bhi(va.y), acc[3]);
            acc[4]  = fmaf(sc, blo(va.z), acc[4]);
            acc[5]  = fmaf(sc, bhi(va.z), acc[5]);
            acc[6]  = fmaf(sc, blo(va.w), acc[6]);
            acc[7]  = fmaf(sc, bhi(va.w), acc[7]);
            acc[8]  = fmaf(sc, blo(vb.x), acc[8]);
            acc[9]  = fmaf(sc, bhi(vb.x), acc[9]);
            acc[10] = fmaf(sc, blo(vb.y), acc[10]);
            acc[11] = fmaf(sc, bhi(vb.y), acc[11]);
            acc[12] = fmaf(sc, blo(vb.z), acc[12]);
            acc[13] = fmaf(sc, bhi(vb.z), acc[13]);
            acc[14] = fmaf(sc, blo(vb.w), acc[14]);
            acc[15] = fmaf(sc, bhi(vb.w), acc[15]);
            z += sc;
            ka = nka; kb = nkb; va = nva; vb = nvb;
        }
    }

#pragma unroll
    for (int j = 0; j < 16; ++j) {
        acc[j] += __shfl_xor(acc[j], 8);
        acc[j] += __shfl_xor(acc[j], 16);
        acc[j] += __shfl_xor(acc[j], 32);
    }
    z += __shfl_xor(z, 8);
    z += __shfl_xor(z, 16);
    z += __shfl_xor(z, 32);

    if (o == 0) {
        float inv = 1.f / z;
        float4* O = (float4*)(out + (size_t)n * HD + p * 16);
        O[0] = (float4){acc[0] * inv,  acc[1] * inv,  acc[2] * inv,  acc[3] * inv};
        O[1] = (float4){acc[4] * inv,  acc[5] * inv,  acc[6] * inv,  acc[7] * inv};
        O[2] = (float4){acc[8] * inv,  acc[9] * inv,  acc[10] * inv, acc[11] * inv};
        O[3] = (float4){acc[12] * inv, acc[13] * inv, acc[14] * inv, acc[15] * inv};
    }
}

// ================= launch ===================================================

static inline char* align256(char* p) {
    return (char*)(((uintptr_t)p + 255) & ~(uintptr_t)255);
}

extern "C" void kernel_launch(void* const* d_in, const int* in_sizes, int n_in,
                              void* d_out, int out_size, void* d_ws, size_t ws_size,
                              hipStream_t stream) {
    const float* h  = (const float*)d_in[0];
    const int*   src = (const int*)d_in[1];
    const int*   dst = (const int*)d_in[2];
    const float* WQ = (const float*)d_in[3];
    const float* WK = (const float*)d_in[4];
    const float* WV = (const float*)d_in[5];
    const float* bQ = (const float*)d_in[6];
    const float* bK = (const float*)d_in[7];
    const float* bV = (const float*)d_in[8];
    float* out = (float*)d_out;

    char* p = (char*)d_ws;
    float* Q = (float*)p;                    p += (size_t)N_PAD * HD * 4;
    unsigned short* Kb = (unsigned short*)p; p += (size_t)N_PAD * HD * 2;
    unsigned short* Vb = (unsigned short*)p; p += (size_t)N_PAD * HD * 2;
    unsigned short* Wf = (unsigned short*)p; p += (size_t)24 * 4 * 64 * 8 * 2;
    p = align256(p);
    int* row_ptr    = (int*)p;               p += (N_NODES + 2) * 4;
    p = align256(p);
    int* bucket_ptr = (int*)p;               p += (NBUCKET + 1) * 4;
    p = align256(p);
    int* btot       = (int*)p;               p += NBUCKET * 4;
    p = align256(p);
    int* chunkhist  = (int*)p;               p += (size_t)NCHUNK * NBUCKET * 4;
    p = align256(p);
    int* chunkoff   = (int*)p;               p += (size_t)NCHUNK * NBUCKET * 4;
    p = align256(p);
    int* packed     = (int*)p;               p += (size_t)N_EDGES * 4;
    p = align256(p);
    int* col_src    = (int*)p;               p += (size_t)N_EDGES * 4;

    (void)hipMemsetAsync(btot, 0, NBUCKET * sizeof(int), stream);
    k_chunkhist<<<NCHUNK + 24, 256, 0, stream>>>(dst, chunkhist, btot, WQ, WK, WV, Wf);
    k_choff<<<NBUCKET, 256, 0, stream>>>(chunkhist, btot, bucket_ptr, chunkoff);
    k_scatter<<<NCHUNK, 256, 0, stream>>>(src, dst, chunkoff, packed);
    k_finalize<<<NBUCKET, 256, 0, stream>>>(bucket_ptr, packed, row_ptr, col_src);
    proj_mfma<<<N_PAD / 64, 256, 0, stream>>>(h, Wf, bQ, bK, bV, Q, Kb, Vb);
    // attention in thirds (diagnostic split; also bounds tail effects)
    const int T1 = 16668, T2 = 33336;
    attn_kernel<<<(T1 + 3) / 4, 256, 0, stream>>>(Q, Kb, Vb, row_ptr, col_src, out, 0, T1);
    attn_kernel<<<(T2 - T1 + 3) / 4, 256, 0, stream>>>(Q, Kb, Vb, row_ptr, col_src, out, T1, T2);
    attn_kernel<<<(N_NODES - T2 + 3) / 4, 256, 0, stream>>>(Q, Kb, Vb, row_ptr, col_src, out, T2, N_NODES);
}